// Round 1
// baseline (110.077 us; speedup 1.0000x reference)
//
#include <hip/hip_runtime.h>

#define EPS 1e-5f
constexpr int B = 4, C = 64, H = 128, W = 256;
constexpr int Hg = 512, Wg = 1024;
constexpr int NC = 19;
constexpr int HW = H * W;      // 32768 pixels per (b,c) plane
constexpr int HW4 = HW / 4;    // 8192 packed-class dwords per batch

typedef float f32x4 __attribute__((ext_vector_type(4)));  // native vec for nt-store

// ---------------- K1: fused pack + per-(b,c,quarter) partial per-class stats --------
// k_pack folded in: every (b,c,q) block must learn its slab's classes anyway, and all
// 64 c-blocks of a (b,q) share the same L2-hot gt lines. So each block unpacks gt
// directly (4 strided dword loads/iter, hidden under the LDS-RMW latency chains);
// the 16 c==0 blocks persist the packed form (gt_p) for k_apply; blocks c<8 each
// histogram their j==c stripe into LDS (fire-and-forget ds_add, ~+6% LDS-pipe
// occupancy on 1/8 of blocks) and write 19-int partials for k_apply to fold.
// Saves the whole k_pack dispatch (~3-5 us incl. graph-node overhead).
__global__ __launch_bounds__(256) void k_stats(const float* __restrict__ x,
                                               const int* __restrict__ gt,
                                               unsigned int* __restrict__ gt_p,
                                               int* __restrict__ counts_pb, // [NC][B][4][8]
                                               float2* __restrict__ par) {  // [19*B*C][4]
  __shared__ float2 acc[NC * 256];   // 38912 B -> still 4 blocks/CU (with hist: 38988 B)
  __shared__ int hist[NC];
  int t = threadIdx.x;
  for (int k = t; k < NC * 256; k += 256) acc[k] = make_float2(0.f, 0.f);
  if (t < NC) hist[t] = 0;
  int plane = blockIdx.x >> 2;       // b*C + c
  int q = blockIdx.x & 3;
  int b = plane >> 6, c = plane & 63;
  __syncthreads();

  const float4* xp = (const float4*)x + (size_t)plane * (HW / 4) + q * 2048;
  // packed dword i (within batch) = q*2048 + j*256 + t  ->  out row h = q*32 + j*4 + (t>>6),
  // out col segment ws = t&63; source gt row = h*4, source cols = ws*16 + {0,4,8,12}.
  int ws = t & 63;
  int h0 = q * 32 + (t >> 6);
  const int* row = gt + (size_t)(b * Hg + h0 * 4) * Wg + ws * 16;
  bool writer = (c == 0);
  unsigned int* gw = gt_p + (size_t)b * HW4 + q * 2048;

#pragma unroll
  for (int j = 0; j < 8; j++) {
    int i = j * 256 + t;
    float4 v = xp[i];
    unsigned int c0 = (unsigned int)row[0];
    unsigned int c1 = (unsigned int)row[4];
    unsigned int c2 = (unsigned int)row[8];
    unsigned int c3 = (unsigned int)row[12];
    row += 16 * Wg;                       // h += 4 per j  ->  gt rows += 16
    if (writer) gw[i] = c0 | (c1 << 8) | (c2 << 16) | (c3 << 24);
    if (c < 8 && j == c) {                // block c histograms its own j==c stripe
      atomicAdd(&hist[c0], 1); atomicAdd(&hist[c1], 1);
      atomicAdd(&hist[c2], 1); atomicAdd(&hist[c3], 1);
    }
    // R2-measured-best LDS scheme: float2 acc[cls*256+t], bank = f(t) only ->
    // conflict-free b64 RMW; chains hidden by 16 waves/CU. (No ds atomics: R3.)
    float2 a;
    a = acc[c0 * 256 + t]; a.x += v.x; a.y += v.x * v.x; acc[c0 * 256 + t] = a;
    a = acc[c1 * 256 + t]; a.x += v.y; a.y += v.y * v.y; acc[c1 * 256 + t] = a;
    a = acc[c2 * 256 + t]; a.x += v.z; a.y += v.z * v.z; acc[c2 * 256 + t] = a;
    a = acc[c3 * 256 + t]; a.x += v.w; a.y += v.w * v.w; acc[c3 * 256 + t] = a;
  }
  __syncthreads();

  if (c < 8 && t < NC) counts_pb[((t * B + b) * 4 + q) * 8 + c] = hist[t];

  // One-barrier reduction: wave w owns classes w, w+4, ... ; 4 LDS reads + butterfly.
  int w = t >> 6, lane = t & 63;
  for (int k = w; k < NC; k += 4) {
    float2 a0 = acc[k * 256 + lane];
    float2 a1 = acc[k * 256 + 64 + lane];
    float2 a2 = acc[k * 256 + 128 + lane];
    float2 a3 = acc[k * 256 + 192 + lane];
    float s  = a0.x + a1.x + a2.x + a3.x;
    float qq = a0.y + a1.y + a2.y + a3.y;
    for (int m = 32; m >= 1; m >>= 1) {
      s  += __shfl_xor(s, m, 64);
      qq += __shfl_xor(qq, m, 64);
    }
    if (lane == 0) {
      int e = (k * B + b) * C + c;
      par[e * 4 + q] = make_float2(s, qq);
    }
  }
}

// ---------------- K2: fused params (threads 0..18) + apply --------------------------
__global__ __launch_bounds__(256) void k_apply(const float* __restrict__ x,
                                               const unsigned int* __restrict__ gt_p,
                                               const float2* __restrict__ par,
                                               const int* __restrict__ counts_pb,
                                               const float* __restrict__ eps_mu,
                                               const float* __restrict__ eps_std,
                                               float* __restrict__ out) {
  __shared__ float2 tab[NC];
  int t = threadIdx.x;
  int plane = blockIdx.x >> 2;     // b*C + c
  int q = blockIdx.x & 3;
  int b = plane >> 6, c = plane & 63;
  const float4* xp = (const float4*)x + (size_t)plane * (HW / 4) + q * 2048;
  const unsigned int* gp = gt_p + (size_t)b * HW4 + q * 2048;
  f32x4* op = (f32x4*)((float4*)out + (size_t)plane * (HW / 4) + q * 2048);

  // prefetch tile j=0 while params compute
  float4 v0 = xp[t];
  unsigned int g0 = gp[t];

  if (t < NC) {                    // redundant tiny per-(cid,c) param math
    float mean[B], stdv[B];
    float msum = 0.f, ssum = 0.f;
#pragma unroll
    for (int bb = 0; bb < B; bb++) {
      // fold the 32 distributed hist partials for (cls=t, bb): L2-hot 128 B
      const int4* cp = (const int4*)&counts_pb[(t * B + bb) * 32];
      int cnt = 0;
#pragma unroll
      for (int j = 0; j < 8; j++) { int4 cv = cp[j]; cnt += cv.x + cv.y + cv.z + cv.w; }
      float n = cnt > 0 ? (float)cnt : 1.f;   // npx = where(npx==0, 1, npx)
      const float4* pp = (const float4*)&par[((t * B + bb) * C + c) * 4];
      float4 p0 = pp[0], p1 = pp[1];
      float s  = (p0.x + p0.z) + (p1.x + p1.z);
      float qq = (p0.y + p0.w) + (p1.y + p1.w);
      float m = s / n;
      float var = qq / n - m * m;             // biased (divide by npx), as reference
      var = var > 0.f ? var : 0.f;
      mean[bb] = m;
      stdv[bb] = sqrtf(var + EPS);
      msum += m; ssum += stdv[bb];
    }
    float mbar = msum * 0.25f, sbar = ssum * 0.25f;
    float vm = 0.f, vs = 0.f;
#pragma unroll
    for (int bb = 0; bb < B; bb++) {
      float dm = mean[bb] - mbar; vm += dm * dm;
      float ds = stdv[bb] - sbar; vs += ds * ds;
    }
    float sqvm = sqrtf(vm * (1.f / 3.f) + EPS);   // ddof=1 over B=4
    float sqvs = sqrtf(vs * (1.f / 3.f) + EPS);
    int e = (t * B + b) * C + c;
    float beta  = mean[b] + eps_mu[e]  * sqvm;
    float gamma = stdv[b] + eps_std[e] * sqvs;
    float sc = gamma / stdv[b];
    tab[t] = make_float2(sc, beta - mean[b] * sc);  // out = x*sc + shift
  }
  __syncthreads();

  {
    float2 a0 = tab[g0 & 255], a1 = tab[(g0 >> 8) & 255];
    float2 a2 = tab[(g0 >> 16) & 255], a3 = tab[g0 >> 24];
    f32x4 o;
    o.x = fmaf(v0.x, a0.x, a0.y);
    o.y = fmaf(v0.y, a1.x, a1.y);
    o.z = fmaf(v0.z, a2.x, a2.y);
    o.w = fmaf(v0.w, a3.x, a3.y);
    __builtin_nontemporal_store(o, &op[t]);   // streaming: don't evict L2-hot x/gt_p
  }
  for (int j = 1; j < 8; j++) {
    int i = j * 256 + t;
    float4 v = xp[i];
    unsigned int g = gp[i];
    float2 a0 = tab[g & 255], a1 = tab[(g >> 8) & 255];
    float2 a2 = tab[(g >> 16) & 255], a3 = tab[g >> 24];
    f32x4 o;
    o.x = fmaf(v.x, a0.x, a0.y);
    o.y = fmaf(v.y, a1.x, a1.y);
    o.z = fmaf(v.z, a2.x, a2.y);
    o.w = fmaf(v.w, a3.x, a3.y);
    __builtin_nontemporal_store(o, &op[i]);
  }
}

extern "C" void kernel_launch(void* const* d_in, const int* in_sizes, int n_in,
                              void* d_out, int out_size, void* d_ws, size_t ws_size,
                              hipStream_t stream) {
  const float* x       = (const float*)d_in[0];
  const int*   gt      = (const int*)  d_in[1];
  const float* eps_mu  = (const float*)d_in[2];
  const float* eps_std = (const float*)d_in[3];
  float* out = (float*)d_out;

  // workspace layout (~296 KB, fully overwritten every call)
  char* ws = (char*)d_ws;
  unsigned int* gt_p     = (unsigned int*)(ws);           // 131072 B packed classes
  int*          counts_pb= (int*)   (ws + 131072);        // 19*4*4*8*4 = 9728 B
  float2*       par      = (float2*)(ws + 140800);        // 19*B*C*4*8 = 155648 B

  hipLaunchKernelGGL(k_stats, dim3(B * C * 4), dim3(256), 0, stream,
                     x, gt, gt_p, counts_pb, par);
  hipLaunchKernelGGL(k_apply, dim3(B * C * 4), dim3(256), 0, stream,
                     x, gt_p, par, counts_pb, eps_mu, eps_std, out);
}

// Round 2
// 101.918 us; speedup vs baseline: 1.0801x; 1.0801x over previous
//
#include <hip/hip_runtime.h>

#define EPS 1e-5f
constexpr int B = 4, C = 64, H = 128, W = 256;
constexpr int Hg = 512, Wg = 1024;
constexpr int NC = 19;
constexpr int HW = H * W;      // 32768 pixels per (b,c) plane
constexpr int HW4 = HW / 4;    // 8192 packed-class dwords per batch

typedef float f32x4 __attribute__((ext_vector_type(4)));  // native vec for nt-store

// ---------------- K1: downsample gt (stride 4), pack classes to u8, histogram -------
// R5 lesson: do NOT fold this into k_stats — every (b,c,q) block re-unpacking raw gt
// costs ~128 MiB of redundant L2 traffic (+8 us measured). The compact gt_p (2 MiB)
// amortizes the unpack exactly once; keep it.
// 256 blocks x 128 threads (block = 2 rows): each thread's 4 loads hit ONE 64B line
// (bytes ws*64 + {0,16,32,48}) -> pure latency, so spread across all 256 CUs.
__global__ __launch_bounds__(128) void k_pack(const int* __restrict__ gt,
                                              unsigned int* __restrict__ gt_p,
                                              int* __restrict__ counts_pb) { // [NC][256]
  __shared__ int hist[NC];
  int t = threadIdx.x;
  if (t < NC) hist[t] = 0;
  __syncthreads();
  int R = blockIdx.x * 2 + (t >> 6);        // global row in [0,512) = b*H + h
  int ws = t & 63;                          // 4-pixel segment within the row
  int b = R >> 7, h = R & 127;
  const int* row = gt + (size_t)(b * Hg + h * 4) * Wg;
  unsigned int c0 = (unsigned int)row[ws * 16 + 0];
  unsigned int c1 = (unsigned int)row[ws * 16 + 4];
  unsigned int c2 = (unsigned int)row[ws * 16 + 8];
  unsigned int c3 = (unsigned int)row[ws * 16 + 12];
  gt_p[R * 64 + ws] = c0 | (c1 << 8) | (c2 << 16) | (c3 << 24);
  atomicAdd(&hist[c0], 1); atomicAdd(&hist[c1], 1);   // classes in [0,19)
  atomicAdd(&hist[c2], 1); atomicAdd(&hist[c3], 1);
  __syncthreads();
  if (t < NC) counts_pb[t * 256 + blockIdx.x] = hist[t];
}

// ---------------- K2: per-(b,c,quarter) partial per-class sum/sumsq -----------------
// R2-measured-best scheme: float2 LDS accumulators acc[cls*256+t] (bank = f(t) only
// -> conflict-free b64 RMW; aliasing chains hidden by 16 waves/CU). LDS-BW-bound
// ~268 MB @ 69 TB/s ~ 4 us. NO ds atomics (R3: terrible), NO register/compare-select
// (R4: VALU floor 8.7 us + shuffle tax measured slower than this).
__global__ __launch_bounds__(256) void k_stats(const float* __restrict__ x,
                                               const unsigned int* __restrict__ gt_p,
                                               const int* __restrict__ counts_pb,
                                               float2* __restrict__ par,   // [19*B*C][4]
                                               int* __restrict__ counts) { // [B*NC]
  __shared__ float2 acc[NC * 256];   // 38912 B -> 4 blocks/CU
  int t = threadIdx.x;
  for (int k = t; k < NC * 256; k += 256) acc[k] = make_float2(0.f, 0.f);
  int plane = blockIdx.x >> 2;       // b*C + c
  int q = blockIdx.x & 3;
  int b = plane >> 6, c = plane & 63;

  // 4 designated blocks fold k_pack's per-block hists -> counts[b][cls]
  if (c == 0 && q == 0 && t < NC) {
    const int4* cp = (const int4*)&counts_pb[t * 256 + b * 64];
    int s = 0;
#pragma unroll
    for (int j = 0; j < 16; j++) { int4 cv = cp[j]; s += cv.x + cv.y + cv.z + cv.w; }
    counts[b * NC + t] = s;
  }
  __syncthreads();

  const float4* xp = (const float4*)x + (size_t)plane * (HW / 4) + q * 2048;
  const unsigned int* gp = gt_p + (size_t)b * HW4 + q * 2048;
  for (int j = 0; j < 8; j++) {
    int i = j * 256 + t;
    float4 v = xp[i];
    unsigned int g = gp[i];
    int c0 = g & 255, c1 = (g >> 8) & 255, c2 = (g >> 16) & 255, c3 = g >> 24;
    float2 a;
    a = acc[c0 * 256 + t]; a.x += v.x; a.y += v.x * v.x; acc[c0 * 256 + t] = a;
    a = acc[c1 * 256 + t]; a.x += v.y; a.y += v.y * v.y; acc[c1 * 256 + t] = a;
    a = acc[c2 * 256 + t]; a.x += v.z; a.y += v.z * v.z; acc[c2 * 256 + t] = a;
    a = acc[c3 * 256 + t]; a.x += v.w; a.y += v.w * v.w; acc[c3 * 256 + t] = a;
  }
  __syncthreads();

  // One-barrier reduction: wave w owns classes w, w+4, ... ; 4 LDS reads + butterfly.
  int w = t >> 6, lane = t & 63;
  for (int k = w; k < NC; k += 4) {
    float2 a0 = acc[k * 256 + lane];
    float2 a1 = acc[k * 256 + 64 + lane];
    float2 a2 = acc[k * 256 + 128 + lane];
    float2 a3 = acc[k * 256 + 192 + lane];
    float s  = a0.x + a1.x + a2.x + a3.x;
    float qq = a0.y + a1.y + a2.y + a3.y;
    for (int m = 32; m >= 1; m >>= 1) {
      s  += __shfl_xor(s, m, 64);
      qq += __shfl_xor(qq, m, 64);
    }
    if (lane == 0) {
      int e = (k * B + b) * C + c;
      par[e * 4 + q] = make_float2(s, qq);
    }
  }
}

// ---------------- K3: fused params (threads 0..18) + apply --------------------------
__global__ __launch_bounds__(256) void k_apply(const float* __restrict__ x,
                                               const unsigned int* __restrict__ gt_p,
                                               const float2* __restrict__ par,
                                               const int* __restrict__ counts,
                                               const float* __restrict__ eps_mu,
                                               const float* __restrict__ eps_std,
                                               float* __restrict__ out) {
  __shared__ float2 tab[NC];
  int t = threadIdx.x;
  int plane = blockIdx.x >> 2;     // b*C + c
  int q = blockIdx.x & 3;
  int b = plane >> 6, c = plane & 63;
  const float4* xp = (const float4*)x + (size_t)plane * (HW / 4) + q * 2048;
  const unsigned int* gp = gt_p + (size_t)b * HW4 + q * 2048;
  f32x4* op = (f32x4*)((float4*)out + (size_t)plane * (HW / 4) + q * 2048);

  // prefetch tile j=0 while params compute
  float4 v0 = xp[t];
  unsigned int g0 = gp[t];

  if (t < NC) {                    // redundant tiny per-(cid,c) param math
    float mean[B], stdv[B];
    float msum = 0.f, ssum = 0.f;
#pragma unroll
    for (int bb = 0; bb < B; bb++) {
      int cnt = counts[bb * NC + t];
      float n = cnt > 0 ? (float)cnt : 1.f;   // npx = where(npx==0, 1, npx)
      const float4* pp = (const float4*)&par[((t * B + bb) * C + c) * 4];
      float4 p0 = pp[0], p1 = pp[1];
      float s  = (p0.x + p0.z) + (p1.x + p1.z);
      float qq = (p0.y + p0.w) + (p1.y + p1.w);
      float m = s / n;
      float var = qq / n - m * m;             // biased (divide by npx), as reference
      var = var > 0.f ? var : 0.f;
      mean[bb] = m;
      stdv[bb] = sqrtf(var + EPS);
      msum += m; ssum += stdv[bb];
    }
    float mbar = msum * 0.25f, sbar = ssum * 0.25f;
    float vm = 0.f, vs = 0.f;
#pragma unroll
    for (int bb = 0; bb < B; bb++) {
      float dm = mean[bb] - mbar; vm += dm * dm;
      float ds = stdv[bb] - sbar; vs += ds * ds;
    }
    float sqvm = sqrtf(vm * (1.f / 3.f) + EPS);   // ddof=1 over B=4
    float sqvs = sqrtf(vs * (1.f / 3.f) + EPS);
    int e = (t * B + b) * C + c;
    float beta  = mean[b] + eps_mu[e]  * sqvm;
    float gamma = stdv[b] + eps_std[e] * sqvs;
    float sc = gamma / stdv[b];
    tab[t] = make_float2(sc, beta - mean[b] * sc);  // out = x*sc + shift
  }
  __syncthreads();

  {
    float2 a0 = tab[g0 & 255], a1 = tab[(g0 >> 8) & 255];
    float2 a2 = tab[(g0 >> 16) & 255], a3 = tab[g0 >> 24];
    f32x4 o;
    o.x = fmaf(v0.x, a0.x, a0.y);
    o.y = fmaf(v0.y, a1.x, a1.y);
    o.z = fmaf(v0.z, a2.x, a2.y);
    o.w = fmaf(v0.w, a3.x, a3.y);
    __builtin_nontemporal_store(o, &op[t]);   // streaming: don't evict L2-hot x/gt_p
  }
  for (int j = 1; j < 8; j++) {
    int i = j * 256 + t;
    float4 v = xp[i];
    unsigned int g = gp[i];
    float2 a0 = tab[g & 255], a1 = tab[(g >> 8) & 255];
    float2 a2 = tab[(g >> 16) & 255], a3 = tab[g >> 24];
    f32x4 o;
    o.x = fmaf(v.x, a0.x, a0.y);
    o.y = fmaf(v.y, a1.x, a1.y);
    o.z = fmaf(v.z, a2.x, a2.y);
    o.w = fmaf(v.w, a3.x, a3.y);
    __builtin_nontemporal_store(o, &op[i]);
  }
}

extern "C" void kernel_launch(void* const* d_in, const int* in_sizes, int n_in,
                              void* d_out, int out_size, void* d_ws, size_t ws_size,
                              hipStream_t stream) {
  const float* x       = (const float*)d_in[0];
  const int*   gt      = (const int*)  d_in[1];
  const float* eps_mu  = (const float*)d_in[2];
  const float* eps_std = (const float*)d_in[3];
  float* out = (float*)d_out;

  // workspace layout (~306 KB, fully overwritten every call)
  char* ws = (char*)d_ws;
  unsigned int* gt_p     = (unsigned int*)(ws);           // 131072 B packed classes
  int*          counts_pb= (int*)   (ws + 131072);        // 19*256*4 = 19456 B
  int*          counts   = (int*)   (ws + 150528);        // 304 B (padded)
  float2*       par      = (float2*)(ws + 150832);        // 19*B*C*4*8 = 155648 B

  hipLaunchKernelGGL(k_pack,  dim3(B * H / 2), dim3(128), 0, stream, gt, gt_p, counts_pb);
  hipLaunchKernelGGL(k_stats, dim3(B * C * 4), dim3(256), 0, stream,
                     x, gt_p, counts_pb, par, counts);
  hipLaunchKernelGGL(k_apply, dim3(B * C * 4), dim3(256), 0, stream,
                     x, gt_p, par, counts, eps_mu, eps_std, out);
}